// Round 4
// baseline (786.912 us; speedup 1.0000x reference)
//
#include <hip/hip_runtime.h>
#include <hip/hip_bf16.h>

#define NB 128
#define LL 512
#define DD 512

typedef __attribute__((ext_vector_type(4))) float  f32x4;
typedef __attribute__((ext_vector_type(8))) short  s16x8;
typedef __attribute__((ext_vector_type(4))) short  s16x4;

__device__ __forceinline__ short f2bf(float f) {
    __hip_bfloat16 h = __float2bfloat16(f);
    return *reinterpret_cast<short*>(&h);
}

// monotone float<->uint mapping so atomicMax(uint) == float max
__device__ __forceinline__ unsigned fmap(float f) {
    unsigned u = __float_as_uint(f);
    return (u & 0x80000000u) ? ~u : (u | 0x80000000u);
}
__device__ __forceinline__ float funmap(unsigned u) {
    unsigned b = (u & 0x80000000u) ? (u ^ 0x80000000u) : ~u;
    return __uint_as_float(b);
}

__global__ __launch_bounds__(256) void init_kernel(unsigned* __restrict__ p, int n) {
    int i = blockIdx.x * 256 + threadIdx.x;
    if (i < n) p[i] = 0u;  // 0 < fmap of any real value
}

// Fused: normalize (on the fly) + 128x128x512 bf16 GEMM + masked row/col max.
// Single-buffered 32KB LDS tile with split barrier -> 4 blocks/CU.
// Staging: fp32 global -> regs -> (fp32 sum-of-squares) -> bf16 -> swizzled LDS.
__global__ __launch_bounds__(256, 4) void simgemm_fused(
        const float* __restrict__ x1, const float* __restrict__ x2,
        const int* __restrict__ mask1, const int* __restrict__ mask2,
        unsigned* __restrict__ rowmax_u, unsigned* __restrict__ colmax_u) {
    __shared__ __align__(16) char lds[33792];
    // A @0 (16KB), B @16384 (16KB), invA @32768 (128 f32), invB @33280
    float* invA_lds = reinterpret_cast<float*>(lds + 32768);
    float* invB_lds = reinterpret_cast<float*>(lds + 33280);

    int bid = blockIdx.x;
    int lid = (bid & 7) * 256 + (bid >> 3);   // XCD-chunked bijective swizzle (nwg=2048)
    int b   = lid >> 4;
    int tr  = (lid >> 2) & 3;
    int tc  = lid & 3;

    int tid  = threadIdx.x;
    int lane = tid & 63;
    int w    = tid >> 6;
    int wr = w >> 1, wc = w & 1;
    int l15 = lane & 15, lhi = lane >> 4;
    int cg = l15, rg = lhi;                   // staging coords: 16 lanes/row-slot, 4 rows/pass

    const float* Ab = x1 + ((size_t)b * LL + tr * 128) * DD;
    const float* Bb = x2 + ((size_t)b * LL + tc * 128) * DD;

    f32x4 ra[8], rb[8];
    float ssa[8], ssb[8];
    #pragma unroll
    for (int i = 0; i < 8; ++i) { ssa[i] = 0.f; ssb[i] = 0.f; }

    f32x4 acc[4][4];
    #pragma unroll
    for (int fr = 0; fr < 4; ++fr)
        #pragma unroll
        for (int fc = 0; fc < 4; ++fc) {
            acc[fr][fc].x = 0.f; acc[fr][fc].y = 0.f;
            acc[fr][fc].z = 0.f; acc[fr][fc].w = 0.f;
        }

    // each thread stages 8 f32x4 of A and 8 of B per 64-wide K-tile:
    // row = w*32 + i*4 + rg, cols cg*4..cg*4+3 of the K-tile
    #define ISSUE(k0)                                                             \
        {                                                                         \
            _Pragma("unroll")                                                     \
            for (int i = 0; i < 8; ++i) {                                         \
                int row = w * 32 + i * 4 + rg;                                    \
                ra[i] = *reinterpret_cast<const f32x4*>(Ab + (size_t)row * DD + (k0) + cg * 4); \
                rb[i] = *reinterpret_cast<const f32x4*>(Bb + (size_t)row * DD + (k0) + cg * 4); \
            }                                                                     \
        }

    #define COMMIT()                                                              \
        {                                                                         \
            char* As_ = lds;                                                      \
            char* Bs_ = lds + 16384;                                              \
            _Pragma("unroll")                                                     \
            for (int i = 0; i < 8; ++i) {                                         \
                int row = w * 32 + i * 4 + rg;                                    \
                unsigned byte = ((unsigned)(row * 128 + cg * 8))                  \
                              ^ ((unsigned)(row & 7) << 4);                       \
                f32x4 va = ra[i];                                                 \
                ssa[i] += va.x*va.x + va.y*va.y + va.z*va.z + va.w*va.w;          \
                s16x4 oa; oa.x = f2bf(va.x); oa.y = f2bf(va.y);                   \
                oa.z = f2bf(va.z); oa.w = f2bf(va.w);                             \
                *reinterpret_cast<s16x4*>(As_ + byte) = oa;                       \
                f32x4 vb = rb[i];                                                 \
                ssb[i] += vb.x*vb.x + vb.y*vb.y + vb.z*vb.z + vb.w*vb.w;          \
                s16x4 ob; ob.x = f2bf(vb.x); ob.y = f2bf(vb.y);                   \
                ob.z = f2bf(vb.z); ob.w = f2bf(vb.w);                             \
                *reinterpret_cast<s16x4*>(Bs_ + byte) = ob;                       \
            }                                                                     \
        }

    // prologue: K-tile 0
    ISSUE(0);
    COMMIT();
    __syncthreads();

    #pragma unroll
    for (int t = 0; t < 8; ++t) {
        if (t < 7) ISSUE((t + 1) * 64);      // loads fly under the MFMA phase
        char* As = lds;
        char* Bs = lds + 16384;
        s16x8 af[2][4], bf[2][4];
        #pragma unroll
        for (int ks = 0; ks < 2; ++ks) {
            #pragma unroll
            for (int fr = 0; fr < 4; ++fr) {
                int row = wr * 64 + fr * 16 + l15;
                unsigned byte = (unsigned)(row * 128 + ks * 64 + lhi * 16)
                              ^ ((unsigned)(row & 7) << 4);
                af[ks][fr] = *reinterpret_cast<const s16x8*>(As + byte);
            }
            #pragma unroll
            for (int fc = 0; fc < 4; ++fc) {
                int crow = wc * 64 + fc * 16 + l15;
                unsigned byte = (unsigned)(crow * 128 + ks * 64 + lhi * 16)
                              ^ ((unsigned)(crow & 7) << 4);
                bf[ks][fc] = *reinterpret_cast<const s16x8*>(Bs + byte);
            }
        }
        __builtin_amdgcn_s_setprio(1);
        #pragma unroll
        for (int ks = 0; ks < 2; ++ks)
            #pragma unroll
            for (int fr = 0; fr < 4; ++fr)
                #pragma unroll
                for (int fc = 0; fc < 4; ++fc)
                    acc[fr][fc] = __builtin_amdgcn_mfma_f32_16x16x32_bf16(
                        af[ks][fr], bf[ks][fc], acc[fr][fc], 0, 0, 0);
        __builtin_amdgcn_s_setprio(0);
        __syncthreads();                      // all LDS reads of this tile done
        if (t < 7) {
            COMMIT();                         // overwrite with tile t+1
            __syncthreads();                  // writes visible
        }
    }

    // ---- inv norms: reduce SS across the 16 lanes sharing each row ----
    #pragma unroll
    for (int i = 0; i < 8; ++i) {
        #pragma unroll
        for (int off = 1; off <= 8; off <<= 1) {
            ssa[i] += __shfl_xor(ssa[i], off, 64);
            ssb[i] += __shfl_xor(ssb[i], off, 64);
        }
    }
    if (cg == 0) {
        #pragma unroll
        for (int i = 0; i < 8; ++i) {
            int row = w * 32 + i * 4 + rg;
            invA_lds[row] = 1.0f / fmaxf(sqrtf(ssa[i]), 1e-8f);
            invB_lds[row] = 1.0f / fmaxf(sqrtf(ssb[i]), 1e-8f);
        }
    }
    __syncthreads();

    // ---- scale by inv norms ----
    float ia[4][4], ib4[4];
    #pragma unroll
    for (int fr = 0; fr < 4; ++fr)
        #pragma unroll
        for (int r = 0; r < 4; ++r)
            ia[fr][r] = invA_lds[wr * 64 + fr * 16 + lhi * 4 + r];
    #pragma unroll
    for (int fc = 0; fc < 4; ++fc)
        ib4[fc] = invB_lds[wc * 64 + fc * 16 + l15];
    #pragma unroll
    for (int fr = 0; fr < 4; ++fr)
        #pragma unroll
        for (int fc = 0; fc < 4; ++fc)
            #pragma unroll
            for (int r = 0; r < 4; ++r)
                acc[fr][fc][r] *= ia[fr][r] * ib4[fc];

    // ---- epilogue: masked row/col maxes ----
    int m2[4];
    #pragma unroll
    for (int fc = 0; fc < 4; ++fc)
        m2[fc] = mask2[b * LL + tc * 128 + wc * 64 + fc * 16 + l15];
    int m1[4][4];
    #pragma unroll
    for (int fr = 0; fr < 4; ++fr)
        #pragma unroll
        for (int r = 0; r < 4; ++r)
            m1[fr][r] = mask1[b * LL + tr * 128 + wr * 64 + fr * 16 + lhi * 4 + r];

    // row max: per (fr,r) max over this wave's 64 cols (mask2-gated)
    #pragma unroll
    for (int fr = 0; fr < 4; ++fr) {
        #pragma unroll
        for (int r = 0; r < 4; ++r) {
            float v = -INFINITY;
            #pragma unroll
            for (int fc = 0; fc < 4; ++fc)
                if (m2[fc]) v = fmaxf(v, acc[fr][fc][r]);
            v = fmaxf(v, __shfl_xor(v, 1, 64));
            v = fmaxf(v, __shfl_xor(v, 2, 64));
            v = fmaxf(v, __shfl_xor(v, 4, 64));
            v = fmaxf(v, __shfl_xor(v, 8, 64));
            if (l15 == 0)
                atomicMax(&rowmax_u[b * LL + tr * 128 + wr * 64 + fr * 16 + lhi * 4 + r],
                          fmap(v));
        }
    }
    // col max: per fc col, max over this wave's 64 rows (mask1-gated)
    #pragma unroll
    for (int fc = 0; fc < 4; ++fc) {
        float v = -INFINITY;
        #pragma unroll
        for (int fr = 0; fr < 4; ++fr)
            #pragma unroll
            for (int r = 0; r < 4; ++r)
                if (m1[fr][r]) v = fmaxf(v, acc[fr][fc][r]);
        v = fmaxf(v, __shfl_xor(v, 16, 64));
        v = fmaxf(v, __shfl_xor(v, 32, 64));
        if (lhi == 0)
            atomicMax(&colmax_u[b * LL + tc * 128 + wc * 64 + fc * 16 + l15], fmap(v));
    }
    #undef ISSUE
    #undef COMMIT
}

__global__ __launch_bounds__(64) void finalize_kernel(
        const unsigned* __restrict__ rowmax_u, const unsigned* __restrict__ colmax_u,
        const int* __restrict__ mask1, const int* __restrict__ mask2,
        float* __restrict__ out) {
    int b = blockIdx.x;
    int lane = threadIdx.x;
    float s1 = 0.f, c1 = 0.f, s2 = 0.f, c2 = 0.f;
    for (int i = lane; i < LL; i += 64) {
        if (mask1[b * LL + i]) { s1 += funmap(rowmax_u[b * LL + i]); c1 += 1.f; }
        if (mask2[b * LL + i]) { s2 += funmap(colmax_u[b * LL + i]); c2 += 1.f; }
    }
    #pragma unroll
    for (int off = 32; off >= 1; off >>= 1) {
        s1 += __shfl_xor(s1, off, 64);
        c1 += __shfl_xor(c1, off, 64);
        s2 += __shfl_xor(s2, off, 64);
        c2 += __shfl_xor(c2, off, 64);
    }
    if (lane == 0) out[b] = 0.5f * (s1 / c1 + s2 / c2);
}

extern "C" void kernel_launch(void* const* d_in, const int* in_sizes, int n_in,
                              void* d_out, int out_size, void* d_ws, size_t ws_size,
                              hipStream_t stream) {
    const float* x1    = (const float*)d_in[0];
    const int*   mask1 = (const int*)d_in[1];
    const float* x2    = (const float*)d_in[2];
    const int*   mask2 = (const int*)d_in[3];
    float* out = (float*)d_out;

    unsigned* rowmax_u = (unsigned*)d_ws;
    unsigned* colmax_u = rowmax_u + NB * LL;

    init_kernel<<<(2 * NB * LL + 255) / 256, 256, 0, stream>>>(rowmax_u, 2 * NB * LL);
    simgemm_fused<<<NB * 16, 256, 0, stream>>>(x1, x2, mask1, mask2,
                                               rowmax_u, colmax_u);
    finalize_kernel<<<NB, 64, 0, stream>>>(rowmax_u, colmax_u, mask1, mask2, out);
}

// Round 5
// 116.596 us; speedup vs baseline: 6.7490x; 6.7490x over previous
//
#include <hip/hip_runtime.h>
#include <hip/hip_bf16.h>

#define NB 128
#define LL 512
#define DD 512

typedef __attribute__((ext_vector_type(4))) float  f32x4;
typedef __attribute__((ext_vector_type(8))) short  s16x8;

#define AS1 __attribute__((address_space(1)))
#define AS3 __attribute__((address_space(3)))

__device__ __forceinline__ short f2bf(float f) {
    __hip_bfloat16 h = __float2bfloat16(f);
    return *reinterpret_cast<short*>(&h);
}

// monotone float<->uint mapping so atomicMax(uint) == float max
__device__ __forceinline__ unsigned fmap(float f) {
    unsigned u = __float_as_uint(f);
    return (u & 0x80000000u) ? ~u : (u | 0x80000000u);
}
__device__ __forceinline__ float funmap(unsigned u) {
    unsigned b = (u & 0x80000000u) ? (u ^ 0x80000000u) : ~u;
    return __uint_as_float(b);
}

__device__ __forceinline__ void gl16(const void* g, void* l) {
    __builtin_amdgcn_global_load_lds((const AS1 unsigned int*)g,
                                     (AS3 unsigned int*)l, 16, 0, 0);
}

__global__ __launch_bounds__(256) void init_kernel(unsigned* __restrict__ p, int n) {
    int i = blockIdx.x * 256 + threadIdx.x;
    if (i < n) p[i] = 0u;  // 0 < fmap of any real value
}

// Stage one 128x32 fp32 K-tile of A and B into LDS via global_load_lds.
// LDS layout per tile: 128 rows x 128 B, 16B slots XOR-swizzled by (row&7).
// Dest is linear (HW requirement); the SOURCE address carries the swizzle.
__device__ __forceinline__ void stage32(
        const float* __restrict__ Ab, const float* __restrict__ Bb,
        int k0, char* lds, int w, int lane) {
    #pragma unroll
    for (int p = 0; p < 4; ++p) {
        int base = p * 4096 + w * 1024;        // wave-uniform LDS byte base
        int L    = base + lane * 16;           // this lane's dest byte
        int row  = L >> 7;                     // 128 B per row
        int slot = ((L >> 4) & 7) ^ (row & 7); // logical 16B slot (4 f32)
        const float* ga = Ab + (size_t)row * DD + k0 + slot * 4;
        gl16(ga, lds + base);                  // HW adds lane*16
        const float* gb = Bb + (size_t)row * DD + k0 + slot * 4;
        gl16(gb, lds + 16384 + base);
    }
}

// Fused: 128x128x512 GEMM (raw fp32 staged -> bf16 fragments) + on-the-fly
// sum-of-squares (from the same fragment registers) + inv-norm scaling +
// masked row/col max. Single 32KB fp32 K-tile buffer, split barrier.
__global__ __launch_bounds__(256, 2) void simgemm_fused(
        const float* __restrict__ x1, const float* __restrict__ x2,
        const int* __restrict__ mask1, const int* __restrict__ mask2,
        unsigned* __restrict__ rowmax_u, unsigned* __restrict__ colmax_u) {
    __shared__ __align__(16) char lds[33792];
    // A @0 (16KB fp32), B @16384 (16KB fp32), invA @32768, invB @33280
    float* invA_lds = reinterpret_cast<float*>(lds + 32768);
    float* invB_lds = reinterpret_cast<float*>(lds + 33280);

    int bid = blockIdx.x;
    int lid = (bid & 7) * 256 + (bid >> 3);   // XCD-chunked bijective swizzle (nwg=2048)
    int b   = lid >> 4;
    int tr  = (lid >> 2) & 3;
    int tc  = lid & 3;

    int tid  = threadIdx.x;
    int lane = tid & 63;
    int w    = tid >> 6;
    int wr = w >> 1, wc = w & 1;
    int l15 = lane & 15, lhi = lane >> 4;

    const float* Ab = x1 + ((size_t)b * LL + tr * 128) * DD;
    const float* Bb = x2 + ((size_t)b * LL + tc * 128) * DD;

    float ssa[4] = {0.f, 0.f, 0.f, 0.f};
    float ssb[4] = {0.f, 0.f, 0.f, 0.f};

    f32x4 acc[4][4];
    #pragma unroll
    for (int fr = 0; fr < 4; ++fr)
        #pragma unroll
        for (int fc = 0; fc < 4; ++fc) {
            acc[fr][fc].x = 0.f; acc[fr][fc].y = 0.f;
            acc[fr][fc].z = 0.f; acc[fr][fc].w = 0.f;
        }

    stage32(Ab, Bb, 0, lds, w, lane);
    __syncthreads();

    for (int t = 0; t < 16; ++t) {
        const char* As = lds;
        const char* Bs = lds + 16384;

        // B fragments: f32 from LDS -> bf16 regs (+ SS for wr==0 waves)
        s16x8 bfr[4];
        #pragma unroll
        for (int fc = 0; fc < 4; ++fc) {
            int crow = wc * 64 + fc * 16 + l15;
            int s0 = (lhi * 2)     ^ (crow & 7);
            int s1 = (lhi * 2 + 1) ^ (crow & 7);
            f32x4 v0 = *reinterpret_cast<const f32x4*>(Bs + crow * 128 + s0 * 16);
            f32x4 v1 = *reinterpret_cast<const f32x4*>(Bs + crow * 128 + s1 * 16);
            if (wr == 0)
                ssb[fc] += v0.x*v0.x + v0.y*v0.y + v0.z*v0.z + v0.w*v0.w
                         + v1.x*v1.x + v1.y*v1.y + v1.z*v1.z + v1.w*v1.w;
            s16x8 o;
            o[0] = f2bf(v0.x); o[1] = f2bf(v0.y); o[2] = f2bf(v0.z); o[3] = f2bf(v0.w);
            o[4] = f2bf(v1.x); o[5] = f2bf(v1.y); o[6] = f2bf(v1.z); o[7] = f2bf(v1.w);
            bfr[fc] = o;
        }
        // A fragments: convert then immediately feed 4 MFMAs (low reg pressure)
        #pragma unroll
        for (int fr = 0; fr < 4; ++fr) {
            int row = wr * 64 + fr * 16 + l15;
            int s0 = (lhi * 2)     ^ (row & 7);
            int s1 = (lhi * 2 + 1) ^ (row & 7);
            f32x4 v0 = *reinterpret_cast<const f32x4*>(As + row * 128 + s0 * 16);
            f32x4 v1 = *reinterpret_cast<const f32x4*>(As + row * 128 + s1 * 16);
            if (wc == 0)
                ssa[fr] += v0.x*v0.x + v0.y*v0.y + v0.z*v0.z + v0.w*v0.w
                         + v1.x*v1.x + v1.y*v1.y + v1.z*v1.z + v1.w*v1.w;
            s16x8 a;
            a[0] = f2bf(v0.x); a[1] = f2bf(v0.y); a[2] = f2bf(v0.z); a[3] = f2bf(v0.w);
            a[4] = f2bf(v1.x); a[5] = f2bf(v1.y); a[6] = f2bf(v1.z); a[7] = f2bf(v1.w);
            #pragma unroll
            for (int fc = 0; fc < 4; ++fc)
                acc[fr][fc] = __builtin_amdgcn_mfma_f32_16x16x32_bf16(
                    a, bfr[fc], acc[fr][fc], 0, 0, 0);
        }

        __syncthreads();                       // all LDS reads of tile t done
        if (t < 15) {
            stage32(Ab, Bb, (t + 1) * 32, lds, w, lane);
            __syncthreads();                   // loads landed (vmcnt drained)
        }
    }

    // ---- inv norms: each row's SS is split across the 4 lhi groups ----
    #pragma unroll
    for (int i = 0; i < 4; ++i) {
        ssa[i] += __shfl_xor(ssa[i], 16, 64);
        ssa[i] += __shfl_xor(ssa[i], 32, 64);
        ssb[i] += __shfl_xor(ssb[i], 16, 64);
        ssb[i] += __shfl_xor(ssb[i], 32, 64);
    }
    if (wc == 0 && lhi == 0) {
        #pragma unroll
        for (int fr = 0; fr < 4; ++fr)
            invA_lds[wr * 64 + fr * 16 + l15] = 1.0f / fmaxf(sqrtf(ssa[fr]), 1e-8f);
    }
    if (wr == 0 && lhi == 0) {
        #pragma unroll
        for (int fc = 0; fc < 4; ++fc)
            invB_lds[wc * 64 + fc * 16 + l15] = 1.0f / fmaxf(sqrtf(ssb[fc]), 1e-8f);
    }
    __syncthreads();

    // ---- scale by inv norms ----
    float ia[4][4], ib4[4];
    #pragma unroll
    for (int fr = 0; fr < 4; ++fr)
        #pragma unroll
        for (int r = 0; r < 4; ++r)
            ia[fr][r] = invA_lds[wr * 64 + fr * 16 + lhi * 4 + r];
    #pragma unroll
    for (int fc = 0; fc < 4; ++fc)
        ib4[fc] = invB_lds[wc * 64 + fc * 16 + l15];
    #pragma unroll
    for (int fr = 0; fr < 4; ++fr)
        #pragma unroll
        for (int fc = 0; fc < 4; ++fc)
            #pragma unroll
            for (int r = 0; r < 4; ++r)
                acc[fr][fc][r] *= ia[fr][r] * ib4[fc];

    // ---- epilogue: masked row/col maxes ----
    int m2[4];
    #pragma unroll
    for (int fc = 0; fc < 4; ++fc)
        m2[fc] = mask2[b * LL + tc * 128 + wc * 64 + fc * 16 + l15];
    int m1[4][4];
    #pragma unroll
    for (int fr = 0; fr < 4; ++fr)
        #pragma unroll
        for (int r = 0; r < 4; ++r)
            m1[fr][r] = mask1[b * LL + tr * 128 + wr * 64 + fr * 16 + lhi * 4 + r];

    // row max: per (fr,r) max over this wave's 64 cols (mask2-gated)
    #pragma unroll
    for (int fr = 0; fr < 4; ++fr) {
        #pragma unroll
        for (int r = 0; r < 4; ++r) {
            float v = -INFINITY;
            #pragma unroll
            for (int fc = 0; fc < 4; ++fc)
                if (m2[fc]) v = fmaxf(v, acc[fr][fc][r]);
            v = fmaxf(v, __shfl_xor(v, 1, 64));
            v = fmaxf(v, __shfl_xor(v, 2, 64));
            v = fmaxf(v, __shfl_xor(v, 4, 64));
            v = fmaxf(v, __shfl_xor(v, 8, 64));
            if (l15 == 0)
                atomicMax(&rowmax_u[b * LL + tr * 128 + wr * 64 + fr * 16 + lhi * 4 + r],
                          fmap(v));
        }
    }
    // col max: per fc col, max over this wave's 64 rows (mask1-gated)
    #pragma unroll
    for (int fc = 0; fc < 4; ++fc) {
        float v = -INFINITY;
        #pragma unroll
        for (int fr = 0; fr < 4; ++fr)
            #pragma unroll
            for (int r = 0; r < 4; ++r)
                if (m1[fr][r]) v = fmaxf(v, acc[fr][fc][r]);
        v = fmaxf(v, __shfl_xor(v, 16, 64));
        v = fmaxf(v, __shfl_xor(v, 32, 64));
        if (lhi == 0)
            atomicMax(&colmax_u[b * LL + tc * 128 + wc * 64 + fc * 16 + l15], fmap(v));
    }
}

__global__ __launch_bounds__(64) void finalize_kernel(
        const unsigned* __restrict__ rowmax_u, const unsigned* __restrict__ colmax_u,
        const int* __restrict__ mask1, const int* __restrict__ mask2,
        float* __restrict__ out) {
    int b = blockIdx.x;
    int lane = threadIdx.x;
    float s1 = 0.f, c1 = 0.f, s2 = 0.f, c2 = 0.f;
    for (int i = lane; i < LL; i += 64) {
        if (mask1[b * LL + i]) { s1 += funmap(rowmax_u[b * LL + i]); c1 += 1.f; }
        if (mask2[b * LL + i]) { s2 += funmap(colmax_u[b * LL + i]); c2 += 1.f; }
    }
    #pragma unroll
    for (int off = 32; off >= 1; off >>= 1) {
        s1 += __shfl_xor(s1, off, 64);
        c1 += __shfl_xor(c1, off, 64);
        s2 += __shfl_xor(s2, off, 64);
        c2 += __shfl_xor(c2, off, 64);
    }
    if (lane == 0) out[b] = 0.5f * (s1 / c1 + s2 / c2);
}

extern "C" void kernel_launch(void* const* d_in, const int* in_sizes, int n_in,
                              void* d_out, int out_size, void* d_ws, size_t ws_size,
                              hipStream_t stream) {
    const float* x1    = (const float*)d_in[0];
    const int*   mask1 = (const int*)d_in[1];
    const float* x2    = (const float*)d_in[2];
    const int*   mask2 = (const int*)d_in[3];
    float* out = (float*)d_out;

    unsigned* rowmax_u = (unsigned*)d_ws;
    unsigned* colmax_u = rowmax_u + NB * LL;

    init_kernel<<<(2 * NB * LL + 255) / 256, 256, 0, stream>>>(rowmax_u, 2 * NB * LL);
    simgemm_fused<<<NB * 16, 256, 0, stream>>>(x1, x2, mask1, mask2,
                                               rowmax_u, colmax_u);
    finalize_kernel<<<NB, 64, 0, stream>>>(rowmax_u, colmax_u, mask1, mask2, out);
}